// Round 5
// baseline (744.549 us; speedup 1.0000x reference)
//
#include <hip/hip_runtime.h>
#include <hip/hip_cooperative_groups.h>

namespace cg = cooperative_groups;

#define BB 128
#define CC 64
#define TT 16384
#define RED 16
#define ROWS (BB * CC)          // 8192
#define T4 (TT / 4)             // 4096 float4 per row
#define GB 16                   // batches per L3-resident group (64 MiB of x)
#define NG (BB / GB)            // 8 groups
#define ROWS_G (GB * CC)        // 1024 rows per group
#define GRID_C 512              // coop grid: 2 rows per block per group

typedef float f4 __attribute__((ext_vector_type(4)));

// One full wave computes s[b][c]; returns sv on ALL lanes.
__device__ __forceinline__ float wave_mlp(const float* __restrict__ u,
                                          const float* __restrict__ w1,
                                          const float* __restrict__ b1,
                                          const float* __restrict__ w2,
                                          const float* __restrict__ b2,
                                          int b, int c, int lane) {
    const int r = lane & 15, q = lane >> 4;      // lane = q*16 + r
    const float* ub  = u  + b * CC + q * 16;
    const float* w1p = w1 + r * CC + q * 16;
    float p = 0.f;
#pragma unroll
    for (int j = 0; j < 16; ++j) p = fmaf(ub[j], w1p[j], p);
    p += __shfl_xor(p, 16, 64);                  // sum 4 q-partials
    p += __shfl_xor(p, 32, 64);                  // -> every lane holds h[r]
    const float h = fmaxf(p + b1[r], 0.f);
    float prod = h * w2[c * RED + r];
    prod += __shfl_xor(prod, 1, 64);             // sum the 16 r's
    prod += __shfl_xor(prod, 2, 64);
    prod += __shfl_xor(prod, 4, 64);
    prod += __shfl_xor(prod, 8, 64);             // all lanes: full dot
    return 1.0f / (1.0f + expf(-(prod + b2[c])));
}

// ================= cooperative single-kernel pipeline =================
__global__ __launch_bounds__(256, 2) void se_fused(
        const f4* __restrict__ x,
        const float* __restrict__ w1, const float* __restrict__ b1,
        const float* __restrict__ w2, const float* __restrict__ b2,
        f4* __restrict__ out, float* __restrict__ s_out,
        float* __restrict__ u) {
    cg::grid_group grid = cg::this_grid();
    const int i = blockIdx.x;                    // 0..511
    const int tid = threadIdx.x;
    const int lane = tid & 63, wid = tid >> 6;
    __shared__ float wsum[2][4];
    __shared__ float s_sh[2];

    // ---- P0: reduce rows i and i+512 of group 0 (HBM read) ----
#pragma unroll
    for (int rr = 0; rr < 2; ++rr) {
        const f4* xr = x + (size_t)(i + rr * GRID_C) * T4;
        float sum = 0.f;
#pragma unroll 4
        for (int k = 0; k < T4 / 256; ++k) {
            f4 v = xr[tid + k * 256];
            sum += (v.x + v.y) + (v.z + v.w);
        }
#pragma unroll
        for (int off = 32; off; off >>= 1) sum += __shfl_down(sum, off, 64);
        if (lane == 0) wsum[rr][wid] = sum;
        __syncthreads();
    }
    if (tid < 2)
        u[i + tid * GRID_C] =
            (wsum[tid][0] + wsum[tid][1] + wsum[tid][2] + wsum[tid][3]) * (1.0f / TT);
    grid.sync();

    for (int g = 0; g < NG; ++g) {
        const int row0 = g * ROWS_G + i;
        // waves 0,1: in-wave MLP for rows row0, row0+512
        if (wid < 2) {
            const int row = row0 + wid * GRID_C;
            const float sv = wave_mlp(u, w1, b1, w2, b2, row >> 6, row & (CC - 1), lane);
            if (lane == 0) { s_sh[wid] = sv; s_out[row] = sv; }
        }
        __syncthreads();

#pragma unroll
        for (int rr = 0; rr < 2; ++rr) {
            const int row = row0 + rr * GRID_C;
            const float sv = s_sh[rr];
            const f4* xr = x + (size_t)row * T4;     // group g: L3 hit expected
            f4* orw = out + (size_t)row * T4;
            if (g + 1 < NG) {
                const f4* xn = x + (size_t)(row + ROWS_G) * T4;  // group g+1: HBM
                float sum = 0.f;
#pragma unroll 4
                for (int k = 0; k < T4 / 256; ++k) {
                    f4 v = xr[tid + k * 256];
                    f4 w = xn[tid + k * 256];
                    v.x *= sv; v.y *= sv; v.z *= sv; v.w *= sv;
                    __builtin_nontemporal_store(v, &orw[tid + k * 256]);
                    sum += (w.x + w.y) + (w.z + w.w);
                }
#pragma unroll
                for (int off = 32; off; off >>= 1) sum += __shfl_down(sum, off, 64);
                if (lane == 0) wsum[rr][wid] = sum;
            } else {
#pragma unroll 4
                for (int k = 0; k < T4 / 256; ++k) {
                    f4 v = xr[tid + k * 256];
                    v.x *= sv; v.y *= sv; v.z *= sv; v.w *= sv;
                    __builtin_nontemporal_store(v, &orw[tid + k * 256]);
                }
            }
        }
        if (g + 1 < NG) {
            __syncthreads();
            if (tid < 2)
                u[row0 + ROWS_G + tid * GRID_C] =
                    (wsum[tid][0] + wsum[tid][1] + wsum[tid][2] + wsum[tid][3]) * (1.0f / TT);
            grid.sync();
        }
    }
}

// ================= non-coop fallback: 1 + NG launches =================
__global__ __launch_bounds__(256) void se_reduce0(const f4* __restrict__ x,
                                                  float* __restrict__ u) {
    const int row = blockIdx.x;                  // group 0 rows
    const int tid = threadIdx.x;
    const int lane = tid & 63, wid = tid >> 6;
    const f4* xr = x + (size_t)row * T4;
    float sum = 0.f;
#pragma unroll 4
    for (int k = 0; k < T4 / 256; ++k) {
        f4 v = xr[tid + k * 256];
        sum += (v.x + v.y) + (v.z + v.w);
    }
#pragma unroll
    for (int off = 32; off; off >>= 1) sum += __shfl_down(sum, off, 64);
    __shared__ float wsum[4];
    if (lane == 0) wsum[wid] = sum;
    __syncthreads();
    if (tid == 0) u[row] = (wsum[0] + wsum[1] + wsum[2] + wsum[3]) * (1.0f / TT);
}

__global__ __launch_bounds__(256) void se_phase(
        const f4* __restrict__ x,
        const float* __restrict__ w1, const float* __restrict__ b1,
        const float* __restrict__ w2, const float* __restrict__ b2,
        f4* __restrict__ out, float* __restrict__ s_out,
        float* __restrict__ u, int g) {
    const int row = g * ROWS_G + blockIdx.x;
    const int tid = threadIdx.x;
    const int lane = tid & 63, wid = tid >> 6;
    __shared__ float wsum[4];
    __shared__ float s_sh;

    if (tid < 64) {
        const float sv = wave_mlp(u, w1, b1, w2, b2, row >> 6, row & (CC - 1), lane);
        if (lane == 0) { s_sh = sv; s_out[row] = sv; }
    }
    __syncthreads();
    const float sv = s_sh;

    const f4* xr = x + (size_t)row * T4;
    f4* orw = out + (size_t)row * T4;
    if (g + 1 < NG) {
        const f4* xn = x + (size_t)(row + ROWS_G) * T4;
        float sum = 0.f;
#pragma unroll 4
        for (int k = 0; k < T4 / 256; ++k) {
            f4 v = xr[tid + k * 256];
            f4 w = xn[tid + k * 256];
            v.x *= sv; v.y *= sv; v.z *= sv; v.w *= sv;
            __builtin_nontemporal_store(v, &orw[tid + k * 256]);
            sum += (w.x + w.y) + (w.z + w.w);
        }
#pragma unroll
        for (int off = 32; off; off >>= 1) sum += __shfl_down(sum, off, 64);
        if (lane == 0) wsum[wid] = sum;
        __syncthreads();
        if (tid == 0)
            u[row + ROWS_G] = (wsum[0] + wsum[1] + wsum[2] + wsum[3]) * (1.0f / TT);
    } else {
#pragma unroll 4
        for (int k = 0; k < T4 / 256; ++k) {
            f4 v = xr[tid + k * 256];
            v.x *= sv; v.y *= sv; v.z *= sv; v.w *= sv;
            __builtin_nontemporal_store(v, &orw[tid + k * 256]);
        }
    }
}

extern "C" void kernel_launch(void* const* d_in, const int* in_sizes, int n_in,
                              void* d_out, int out_size, void* d_ws, size_t ws_size,
                              hipStream_t stream) {
    const f4*    x  = (const f4*)d_in[0];
    const float* w1 = (const float*)d_in[1];
    const float* b1 = (const float*)d_in[2];
    const float* w2 = (const float*)d_in[3];
    const float* b2 = (const float*)d_in[4];

    f4*    out   = (f4*)d_out;                   // [B*C*T] x_recal, then [B*C] s
    float* s_out = (float*)d_out + (size_t)ROWS * TT;
    float* u_ws  = (float*)d_ws;                 // [B*C] means

    void* args[] = {(void*)&x, (void*)&w1, (void*)&b1, (void*)&w2, (void*)&b2,
                    (void*)&out, (void*)&s_out, (void*)&u_ws};
    hipError_t err = hipLaunchCooperativeKernel((const void*)se_fused,
                                                dim3(GRID_C), dim3(256),
                                                args, 0, stream);
    if (err != hipSuccess) {
        // deterministic fallback: same math, kernel-boundary syncs
        se_reduce0<<<ROWS_G, 256, 0, stream>>>(x, u_ws);
        for (int g = 0; g < NG; ++g)
            se_phase<<<ROWS_G, 256, 0, stream>>>(x, w1, b1, w2, b2,
                                                 out, s_out, u_ws, g);
    }
}

// Round 6
// 265.094 us; speedup vs baseline: 2.8086x; 2.8086x over previous
//
#include <hip/hip_runtime.h>

#define BB 128
#define CC 64
#define TT 16384
#define RED 16
#define ROWS (BB * CC)          // 8192
#define T4 (TT / 4)             // 4096 float4 per row
#define GB 16                   // batches per L3-resident group (64 MiB of x)
#define NG (BB / GB)            // 8 groups
#define ROWS_G (GB * CC)        // 1024 rows per group == grid per launch

typedef float f4 __attribute__((ext_vector_type(4)));

// One full wave computes s[b][c]; returns sv on ALL lanes.
__device__ __forceinline__ float wave_mlp(const float* __restrict__ u,
                                          const float* __restrict__ w1,
                                          const float* __restrict__ b1,
                                          const float* __restrict__ w2,
                                          const float* __restrict__ b2,
                                          int b, int c, int lane) {
    const int r = lane & 15, q = lane >> 4;      // lane = q*16 + r
    const float* ub  = u  + b * CC + q * 16;
    const float* w1p = w1 + r * CC + q * 16;
    float p = 0.f;
#pragma unroll
    for (int j = 0; j < 16; ++j) p = fmaf(ub[j], w1p[j], p);
    p += __shfl_xor(p, 16, 64);                  // sum 4 q-partials
    p += __shfl_xor(p, 32, 64);                  // -> every lane holds h[r]
    const float h = fmaxf(p + b1[r], 0.f);
    float prod = h * w2[c * RED + r];
    prod += __shfl_xor(prod, 1, 64);             // sum the 16 r's
    prod += __shfl_xor(prod, 2, 64);
    prod += __shfl_xor(prod, 4, 64);
    prod += __shfl_xor(prod, 8, 64);
    return 1.0f / (1.0f + expf(-(prod + b2[c])));
}

// ---------------- kernel 1: mean of group-0 rows (HBM read) ----------------
__global__ __launch_bounds__(256) void se_reduce0(const f4* __restrict__ x,
                                                  float* __restrict__ u) {
    const int row = blockIdx.x;
    const int tid = threadIdx.x;
    const int lane = tid & 63, wid = tid >> 6;
    const f4* xr = x + (size_t)row * T4;
    float s0 = 0.f, s1 = 0.f;
#pragma unroll 8
    for (int k = 0; k < T4 / 256; k += 2) {
        f4 a = xr[tid + k * 256];
        f4 b = xr[tid + (k + 1) * 256];
        s0 += (a.x + a.y) + (a.z + a.w);
        s1 += (b.x + b.y) + (b.z + b.w);
    }
    float sum = s0 + s1;
#pragma unroll
    for (int off = 32; off; off >>= 1) sum += __shfl_down(sum, off, 64);
    __shared__ float wsum[4];
    if (lane == 0) wsum[wid] = sum;
    __syncthreads();
    if (tid == 0) u[row] = (wsum[0] + wsum[1] + wsum[2] + wsum[3]) * (1.0f / TT);
}

// ---- kernel 2 (x8): {reduce group g+1 from HBM} + {MLP + scale group g from L3} ----
__global__ __launch_bounds__(256) void se_phase(
        const f4* __restrict__ x,
        const float* __restrict__ w1, const float* __restrict__ b1,
        const float* __restrict__ w2, const float* __restrict__ b2,
        f4* __restrict__ out, float* __restrict__ s_out,
        float* __restrict__ u, int g) {
    const int row = g * ROWS_G + blockIdx.x;
    const int tid = threadIdx.x;
    const int lane = tid & 63, wid = tid >> 6;
    __shared__ float wsum[4];
    __shared__ float s_sh;

    // wave 0: excitation MLP for this row (u is L2-hot from previous launch)
    if (wid == 0) {
        const float sv = wave_mlp(u, w1, b1, w2, b2, row >> 6, row & (CC - 1), lane);
        if (lane == 0) { s_sh = sv; s_out[row] = sv; }
    }

    // all waves: reduce row+ROWS_G (group g+1) — pure HBM read stream
    if (g + 1 < NG) {
        const f4* xn = x + (size_t)(row + ROWS_G) * T4;
        float s0 = 0.f, s1 = 0.f;
#pragma unroll 8
        for (int k = 0; k < T4 / 256; k += 2) {
            f4 a = xn[tid + k * 256];
            f4 b = xn[tid + (k + 1) * 256];
            s0 += (a.x + a.y) + (a.z + a.w);
            s1 += (b.x + b.y) + (b.z + b.w);
        }
        float sum = s0 + s1;
#pragma unroll
        for (int off = 32; off; off >>= 1) sum += __shfl_down(sum, off, 64);
        if (lane == 0) wsum[wid] = sum;
    }
    __syncthreads();                             // s_sh + wsum ready
    if (g + 1 < NG && tid == 0)
        u[row + ROWS_G] = (wsum[0] + wsum[1] + wsum[2] + wsum[3]) * (1.0f / TT);

    // all waves: scale group-g row — reads served by L3, nt-stores to HBM
    const float sv = s_sh;
    const f4* xr = x + (size_t)row * T4;
    f4* orw = out + (size_t)row * T4;
#pragma unroll 8
    for (int k = 0; k < T4 / 256; ++k) {
        f4 v = xr[tid + k * 256];
        v.x *= sv; v.y *= sv; v.z *= sv; v.w *= sv;
        __builtin_nontemporal_store(v, &orw[tid + k * 256]);
    }
}

extern "C" void kernel_launch(void* const* d_in, const int* in_sizes, int n_in,
                              void* d_out, int out_size, void* d_ws, size_t ws_size,
                              hipStream_t stream) {
    const f4*    x  = (const f4*)d_in[0];
    const float* w1 = (const float*)d_in[1];
    const float* b1 = (const float*)d_in[2];
    const float* w2 = (const float*)d_in[3];
    const float* b2 = (const float*)d_in[4];

    f4*    out   = (f4*)d_out;                   // [B*C*T] x_recal, then [B*C] s
    float* s_out = (float*)d_out + (size_t)ROWS * TT;
    float* u_ws  = (float*)d_ws;                 // [B*C] means

    se_reduce0<<<ROWS_G, 256, 0, stream>>>(x, u_ws);
    for (int g = 0; g < NG; ++g)
        se_phase<<<ROWS_G, 256, 0, stream>>>(x, w1, b1, w2, b2,
                                             out, s_out, u_ws, g);
}